// Round 5
// baseline (458.425 us; speedup 1.0000x reference)
//
#include <hip/hip_runtime.h>

typedef __bf16 bf16x8 __attribute__((ext_vector_type(8)));
typedef float f32x4 __attribute__((ext_vector_type(4)));
typedef unsigned short ushort8v __attribute__((ext_vector_type(8)));

#define NB 16
#define NT 4096
#define NV 32000
#define ND 512
#define NH 1024
#define NSLOTS 256

__device__ __forceinline__ float b2f(unsigned short u) {
  unsigned int x = ((unsigned int)u) << 16;
  return __builtin_bit_cast(float, x);
}
__device__ __forceinline__ unsigned short f2b(float f) {
  unsigned int x = __builtin_bit_cast(unsigned int, f);
  unsigned int r = (x + 0x7FFFu + ((x >> 16) & 1u)) >> 16;
  return (unsigned short)r;
}

#define GLOAD_LDS16(g, l)                                                              \
  __builtin_amdgcn_global_load_lds((const __attribute__((address_space(1))) void*)(g), \
                                   (__attribute__((address_space(3))) void*)(l), 16, 0, 0)

// ---------------------------------------------------------------------------
// Fused elementwise prep: emb f32->bf16 (blocks <8000) and w1/w2 transpose+cvt.
// ---------------------------------------------------------------------------
__global__ __launch_bounds__(256) void cvtwt_kernel(
    const float* __restrict__ emb, unsigned short* __restrict__ embb,
    const float* __restrict__ w1, const float* __restrict__ w2,
    unsigned short* __restrict__ w1t, unsigned short* __restrict__ w2t) {
  const int blk = blockIdx.x;
  if (blk < 8000) {
    const long base = ((long)blk * 256 + threadIdx.x) * 8;
    float4 a = *(const float4*)&emb[base];
    float4 b = *(const float4*)&emb[base + 4];
    ushort8v o;
    o[0] = f2b(a.x); o[1] = f2b(a.y); o[2] = f2b(a.z); o[3] = f2b(a.w);
    o[4] = f2b(b.x); o[5] = f2b(b.y); o[6] = f2b(b.z); o[7] = f2b(b.w);
    *(ushort8v*)&embb[base] = o;
  } else {
    const int i = (blk - 8000) * 256 + threadIdx.x;
    if (i < ND * NH) {
      const int n = i >> 9, k = i & 511;
      w1t[i] = f2b(w1[k * NH + n]);
    } else {
      const int j = i - ND * NH;
      const int n = j >> 10, k = j & 1023;
      w2t[j] = f2b(w2[k * ND + n]);
    }
  }
}

// ---------------------------------------------------------------------------
// Tiled bf16 MFMA GEMM: Out = act(A @ Bt^T + bias) -> bf16.
// Tile 128x128, BK=32, 3-deep buffer pipeline with counted vmcnt (loads stay
// in flight across raw s_barriers), XOR-swizzled LDS (linear gload_lds dest +
// pre-swizzled global src + swizzled ds_read), XCD-aware block swizzle,
// setprio around MFMA cluster. 4 waves (2x2).
// ---------------------------------------------------------------------------
template <int KDIM, int NLD, int NBN, bool GATHER, bool RELU>
__global__ __launch_bounds__(256) void gemm_kernel(
    const int* __restrict__ seq, const unsigned short* __restrict__ Abase,
    const unsigned short* __restrict__ Bt, const float* __restrict__ bias,
    unsigned short* __restrict__ Out) {
  __shared__ union {
    unsigned short AB[3][2][128 * 32];  // [buf][A/B][row*32 + chunk*8]
    unsigned short C[128 * 136];        // padded epilogue tile
  } sm;
  const int tid = threadIdx.x;
  const int lane = tid & 63;
  const int w = tid >> 6;

  // XCD-aware bijective swizzle (gridDim.x % 8 == 0)
  const int id = blockIdx.x;
  const int swz = (id & 7) * (gridDim.x >> 3) + (id >> 3);
  const int bm = swz / NBN;
  const int bn = swz % NBN;

  const int wm = w >> 1, wn = w & 1;

  // Staging: wave w stages row-groups {2w,2w+1} of A and B.
  // LDS slot (row, c) holds global chunk c ^ ((row>>1)&3)  (pre-swizzled src).
  const int rgrp = lane >> 2;
  const int schunk = (lane & 3) ^ ((lane >> 3) & 3);
  const unsigned short* aptr[2];
  const unsigned short* bptr[2];
#pragma unroll
  for (int r = 0; r < 2; ++r) {
    const int grp = w * 2 + r;
    const int arow = bm * 128 + grp * 16 + rgrp;
    if constexpr (GATHER)
      aptr[r] = Abase + (size_t)seq[arow] * (size_t)KDIM + schunk * 8;
    else
      aptr[r] = Abase + (size_t)arow * (size_t)KDIM + schunk * 8;
    const int brow = bn * 128 + grp * 16 + rgrp;
    bptr[r] = Bt + (size_t)brow * (size_t)KDIM + schunk * 8;
  }

  // Fragment read offsets (shorts), same swizzle on the read side.
  const int fr = lane & 15;
  const int fhi = lane >> 4;
  const int fsw = (fr >> 1) & 3;
  const int fchunk = (fhi ^ fsw) * 8;
  int aoff[4], boff[4];
#pragma unroll
  for (int m = 0; m < 4; ++m) aoff[m] = (wm * 64 + m * 16 + fr) * 32 + fchunk;
#pragma unroll
  for (int n = 0; n < 4; ++n) boff[n] = (wn * 64 + n * 16 + fr) * 32 + fchunk;

  f32x4 acc[4][4] = {};

  auto stage = [&](int buf, int kt) {
#pragma unroll
    for (int r = 0; r < 2; ++r) {
      const int grp = w * 2 + r;
      GLOAD_LDS16(aptr[r] + kt * 32, &sm.AB[buf][0][grp * 512]);
      GLOAD_LDS16(bptr[r] + kt * 32, &sm.AB[buf][1][grp * 512]);
    }
  };

  constexpr int NKT = KDIM / 32;
  stage(0, 0);
  stage(1, 1);
  for (int kt = 0; kt < NKT; ++kt) {
    // Retire stage kt (4 loads/thread); leave stage kt+1 in flight across barrier.
    if (kt + 1 < NKT)
      asm volatile("s_waitcnt vmcnt(4)" ::: "memory");
    else
      asm volatile("s_waitcnt vmcnt(0)" ::: "memory");
    __builtin_amdgcn_s_barrier();
    if (kt + 2 < NKT) stage((kt + 2) % 3, kt + 2);
    const int cur = kt % 3;
    bf16x8 af[4], bfr[4];
#pragma unroll
    for (int m = 0; m < 4; ++m)
      af[m] = __builtin_bit_cast(bf16x8, *(const ushort8v*)&sm.AB[cur][0][aoff[m]]);
#pragma unroll
    for (int n = 0; n < 4; ++n)
      bfr[n] = __builtin_bit_cast(bf16x8, *(const ushort8v*)&sm.AB[cur][1][boff[n]]);
    __builtin_amdgcn_s_setprio(1);
#pragma unroll
    for (int m = 0; m < 4; ++m)
#pragma unroll
      for (int n = 0; n < 4; ++n)
        acc[m][n] = __builtin_amdgcn_mfma_f32_16x16x32_bf16(af[m], bfr[n], acc[m][n], 0, 0, 0);
    __builtin_amdgcn_s_setprio(0);
  }
  __builtin_amdgcn_s_barrier();  // all waves done reading AB before C reuses LDS

  // Epilogue: bias (+relu), repack C through padded LDS for 16B stores.
#pragma unroll
  for (int m = 0; m < 4; ++m)
#pragma unroll
    for (int n = 0; n < 4; ++n) {
      const int col_l = wn * 64 + n * 16 + fr;
      const float bb = bias[bn * 128 + col_l];
      const int row_l0 = wm * 64 + m * 16 + (fhi << 2);
#pragma unroll
      for (int i = 0; i < 4; ++i) {
        float v = acc[m][n][i] + bb;
        if constexpr (RELU) v = fmaxf(v, 0.f);
        sm.C[(row_l0 + i) * 136 + col_l] = f2b(v);
      }
    }
  __syncthreads();
#pragma unroll
  for (int r8 = 0; r8 < 8; ++r8) {
    const int chunk = r8 * 256 + tid;
    const int row = chunk >> 4;
    const int c8 = (chunk & 15) * 8;
    ushort8v v = *(const ushort8v*)&sm.C[row * 136 + c8];
    *(ushort8v*)&Out[(size_t)(bm * 128 + row) * (size_t)NLD + bn * 128 + c8] = v;
  }
}

// ---------------------------------------------------------------------------
// Fused residual + LayerNorm + gate (f32 math).
// ---------------------------------------------------------------------------
__global__ __launch_bounds__(256) void ln_gate_kernel(
    const int* __restrict__ seq, const float* __restrict__ emb,
    const unsigned short* __restrict__ FF, unsigned short* __restrict__ H,
    const float* __restrict__ ln_g, const float* __restrict__ ln_b,
    const float* __restrict__ wg, const float* __restrict__ bgp,
    float* __restrict__ gate, float* __restrict__ hlast) {
  const int lane = threadIdx.x & 63;
  const int w = threadIdx.x >> 6;
  const int t = blockIdx.x * 4 + w;
  const float* er = emb + (size_t)seq[t] * ND + lane * 8;
  ushort8v fv = *(const ushort8v*)&FF[(size_t)t * ND + lane * 8];
  float4 e0 = *(const float4*)er, e1 = *(const float4*)(er + 4);
  float x[8] = {b2f(fv[0]) + e0.x, b2f(fv[1]) + e0.y, b2f(fv[2]) + e0.z, b2f(fv[3]) + e0.w,
                b2f(fv[4]) + e1.x, b2f(fv[5]) + e1.y, b2f(fv[6]) + e1.z, b2f(fv[7]) + e1.w};
  float s = 0.f, sq = 0.f;
#pragma unroll
  for (int j = 0; j < 8; ++j) {
    s += x[j];
    sq += x[j] * x[j];
  }
#pragma unroll
  for (int o = 32; o; o >>= 1) {
    s += __shfl_xor(s, o);
    sq += __shfl_xor(sq, o);
  }
  const float mu = s * (1.f / 512.f);
  const float var = sq * (1.f / 512.f) - mu * mu;
  const float rs = rsqrtf(var + 1e-5f);
  float gd = 0.f;
  float h[8];
  ushort8v hv;
#pragma unroll
  for (int j = 0; j < 8; ++j) {
    const int col = lane * 8 + j;
    h[j] = (x[j] - mu) * rs * ln_g[col] + ln_b[col];
    hv[j] = f2b(h[j]);
    gd += h[j] * wg[col];
  }
  *(ushort8v*)&H[(size_t)t * ND + lane * 8] = hv;
#pragma unroll
  for (int o = 32; o; o >>= 1) gd += __shfl_xor(gd, o);
  if (lane == 0) gate[t] = 1.f / (1.f + expf(-(gd + bgp[0])));
  if ((t & (NT - 1)) == NT - 1) {
    const int b = t >> 12;
    float* hl = hlast + b * ND + lane * 8;
#pragma unroll
    for (int j = 0; j < 8; ++j) hl[j] = h[j];
  }
}

// ---------------------------------------------------------------------------
// Top-256 of 4096 per batch: radix threshold search on positive f32 bits.
// Deterministic, ties by lowest index.
// ---------------------------------------------------------------------------
__global__ __launch_bounds__(256) void topk_kernel(const float* __restrict__ gate,
                                                   int* __restrict__ topidx) {
  __shared__ unsigned int keys[NT];
  __shared__ int cnt;
  __shared__ int scan[256];
  const int b = blockIdx.x, tid = threadIdx.x;
  const float* g = gate + (size_t)b * NT;
  for (int i = tid; i < NT; i += 256) keys[i] = __builtin_bit_cast(unsigned int, g[i]);
  __syncthreads();
  unsigned int K = 0u;
  for (int bit = 31; bit >= 0; --bit) {
    const unsigned int cand = K | (1u << bit);
    if (tid == 0) cnt = 0;
    __syncthreads();
    int c = 0;
    for (int i = tid * 16; i < tid * 16 + 16; ++i) c += (keys[i] >= cand) ? 1 : 0;
    if (c) atomicAdd(&cnt, c);
    __syncthreads();
    const int cn = cnt;
    __syncthreads();
    if (cn >= NSLOTS) K = cand;
  }
  int gcnt = 0, ecnt = 0;
  for (int i = tid * 16; i < tid * 16 + 16; ++i) {
    gcnt += (keys[i] > K) ? 1 : 0;
    ecnt += (keys[i] == K) ? 1 : 0;
  }
  scan[tid] = gcnt;
  __syncthreads();
  for (int off = 1; off < 256; off <<= 1) {
    int v2 = (tid >= off) ? scan[tid - off] : 0;
    __syncthreads();
    scan[tid] += v2;
    __syncthreads();
  }
  const int gi = scan[tid];
  const int tot_gt = scan[255];
  __syncthreads();
  scan[tid] = ecnt;
  __syncthreads();
  for (int off = 1; off < 256; off <<= 1) {
    int v2 = (tid >= off) ? scan[tid - off] : 0;
    __syncthreads();
    scan[tid] += v2;
    __syncthreads();
  }
  const int ei = scan[tid];
  int gpos = gi - gcnt;
  int epos = tot_gt + (ei - ecnt);
  int* outp = topidx + b * NSLOTS;
  for (int i = tid * 16; i < tid * 16 + 16; ++i) {
    if (keys[i] > K) {
      outp[gpos++] = i;
    } else if (keys[i] == K) {
      if (epos < NSLOTS) outp[epos] = i;
      epos++;
    }
  }
}

// ---------------------------------------------------------------------------
// Fused q + scores + softmax + ctx (one block per batch; H is bf16).
// q = hlast @ wq + bq computed into LDS first.
// ---------------------------------------------------------------------------
__global__ __launch_bounds__(256) void attn_kernel(
    const unsigned short* __restrict__ H, const float* __restrict__ hlast,
    const float* __restrict__ wq, const float* __restrict__ bq,
    const int* __restrict__ topidx, float* __restrict__ ctx) {
  __shared__ float hl[512];
  __shared__ float qs[512];
  __shared__ float attn[256];
  __shared__ int idxs[256];
  __shared__ float red[4];
  const int b = blockIdx.x, tid = threadIdx.x;
  const int lane = tid & 63, wv = tid >> 6;
  hl[tid] = hlast[b * 512 + tid];
  hl[256 + tid] = hlast[b * 512 + 256 + tid];
  idxs[tid] = topidx[b * 256 + tid];
  __syncthreads();
  // q: each thread owns cols tid and tid+256
  {
    float a0 = bq[tid], a1 = bq[tid + 256];
    for (int d = 0; d < 512; ++d) {
      const float hv = hl[d];
      a0 += hv * wq[d * 512 + tid];
      a1 += hv * wq[d * 512 + tid + 256];
    }
    qs[tid] = a0;
    qs[tid + 256] = a1;
  }
  __syncthreads();
  const unsigned short* hr = H + ((size_t)b * NT + idxs[tid]) * ND;
  float sc = 0.f;
  for (int d0 = 0; d0 < 512; d0 += 8) {
    ushort8v hv = *(const ushort8v*)&hr[d0];
#pragma unroll
    for (int j = 0; j < 8; ++j) sc += b2f(hv[j]) * qs[d0 + j];
  }
  float m = sc;
#pragma unroll
  for (int o = 32; o; o >>= 1) m = fmaxf(m, __shfl_xor(m, o));
  if (lane == 0) red[wv] = m;
  __syncthreads();
  m = fmaxf(fmaxf(red[0], red[1]), fmaxf(red[2], red[3]));
  __syncthreads();
  const float e = expf(sc - m);
  float ssum = e;
#pragma unroll
  for (int o = 32; o; o >>= 1) ssum += __shfl_xor(ssum, o);
  if (lane == 0) red[wv] = ssum;
  __syncthreads();
  ssum = red[0] + red[1] + red[2] + red[3];
  attn[tid] = e / ssum;
  __syncthreads();
  for (int d = tid; d < 512; d += 256) {
    float c = 0.f;
    for (int k = 0; k < 256; ++k) c += attn[k] * b2f(H[((size_t)b * NT + idxs[k]) * ND + d]);
    ctx[b * 512 + d] = c;
  }
}

// ---------------------------------------------------------------------------
// out = ctx @ wo + bo  (f32). 250 blocks x 128 cols; 2-way D-split per block.
// ---------------------------------------------------------------------------
__global__ __launch_bounds__(256) void out_kernel(const float* __restrict__ ctx,
                                                  const float* __restrict__ wo,
                                                  const float* __restrict__ bo,
                                                  float* __restrict__ out) {
  __shared__ float cs[16 * 512];
  __shared__ float part[16 * 128];
  const int tid = threadIdx.x;
  const int col = tid & 127;
  const int v = blockIdx.x * 128 + col;
  for (int i = tid; i < 16 * 512; i += 256) cs[i] = ctx[i];
  __syncthreads();
  const int dh = (tid >> 7) * 256;  // 0 or 256
  float acc[16] = {};
  for (int d = dh; d < dh + 256; ++d) {
    const float wv = wo[(size_t)d * NV + v];
#pragma unroll
    for (int bb = 0; bb < 16; ++bb) acc[bb] += cs[bb * 512 + d] * wv;
  }
  if (tid >= 128) {
#pragma unroll
    for (int bb = 0; bb < 16; ++bb) part[bb * 128 + col] = acc[bb];
  }
  __syncthreads();
  if (tid < 128) {
    const float bov = bo[v];
#pragma unroll
    for (int bb = 0; bb < 16; ++bb)
      out[(size_t)bb * NV + v] = acc[bb] + part[bb * 128 + col] + bov;
  }
}

// ---------------------------------------------------------------------------
// Workspace layout (total 194.0 MiB):
//   A1     @ 0          : 65536x1024 bf16 = 128 MiB (gemm1 out; later aliased as H)
//   region @ 128 MiB    : 64 MiB — embb (phase 1), then FF bf16 (phase 2)
//   w1t    @ 192 MiB    : 1 MiB — dead after gemm1; aliased by small buffers
//   w2t    @ 193 MiB    : 1 MiB — dead after gemm2
// ---------------------------------------------------------------------------
extern "C" void kernel_launch(void* const* d_in, const int* in_sizes, int n_in,
                              void* d_out, int out_size, void* d_ws, size_t ws_size,
                              hipStream_t stream) {
  const int* seq = (const int*)d_in[0];
  const float* emb = (const float*)d_in[1];
  const float* w1 = (const float*)d_in[2];
  const float* b1 = (const float*)d_in[3];
  const float* w2 = (const float*)d_in[4];
  const float* b2 = (const float*)d_in[5];
  const float* ln_g = (const float*)d_in[6];
  const float* ln_b = (const float*)d_in[7];
  const float* wg = (const float*)d_in[8];
  const float* bg = (const float*)d_in[9];
  const float* wq = (const float*)d_in[10];
  const float* bq = (const float*)d_in[11];
  const float* wo = (const float*)d_in[12];
  const float* bo = (const float*)d_in[13];
  float* out = (float*)d_out;

  char* ws = (char*)d_ws;
  unsigned short* A1 = (unsigned short*)ws;                       // 128 MiB
  unsigned short* region = (unsigned short*)(ws + ((size_t)128 << 20));
  unsigned short* embb = region;                                  // phase 1
  unsigned short* FF = region;                                    // phase 2
  unsigned short* w1t = (unsigned short*)(ws + ((size_t)192 << 20));
  unsigned short* w2t = (unsigned short*)(ws + ((size_t)193 << 20));
  char* sb = ws + ((size_t)192 << 20);
  float* gate = (float*)sb;                                       // 256 KiB
  int* topidx = (int*)(sb + 262144);                              // 16 KiB
  float* hlast = (float*)(sb + 262144 + 16384);                   // 32 KiB
  float* ctxbuf = (float*)(sb + 262144 + 16384 + 32768);          // 32 KiB
  unsigned short* H = A1;                                         // A1 dead after gemm2

  cvtwt_kernel<<<12096, 256, 0, stream>>>(emb, embb, w1, w2, w1t, w2t);
  gemm_kernel<512, 1024, 8, true, true>
      <<<4096, 256, 0, stream>>>(seq, embb, w1t, b1, A1);
  gemm_kernel<1024, 512, 4, false, false>
      <<<2048, 256, 0, stream>>>(nullptr, A1, w2t, b2, FF);
  ln_gate_kernel<<<16384, 256, 0, stream>>>(seq, emb, FF, H, ln_g, ln_b, wg, bg, gate, hlast);
  topk_kernel<<<16, 256, 0, stream>>>(gate, topidx);
  attn_kernel<<<16, 256, 0, stream>>>(H, hlast, wq, bq, topidx, ctxbuf);
  out_kernel<<<250, 256, 0, stream>>>(ctxbuf, wo, bo, out);
}

// Round 6
// 357.715 us; speedup vs baseline: 1.2815x; 1.2815x over previous
//
#include <hip/hip_runtime.h>

typedef __bf16 bf16x8 __attribute__((ext_vector_type(8)));
typedef float f32x4 __attribute__((ext_vector_type(4)));
typedef unsigned short ushort8v __attribute__((ext_vector_type(8)));

#define NB 16
#define NT 4096
#define NV 32000
#define ND 512
#define NH 1024
#define NSLOTS 256

__device__ __forceinline__ float b2f(unsigned short u) {
  unsigned int x = ((unsigned int)u) << 16;
  return __builtin_bit_cast(float, x);
}
__device__ __forceinline__ unsigned short f2b(float f) {
  unsigned int x = __builtin_bit_cast(unsigned int, f);
  unsigned int r = (x + 0x7FFFu + ((x >> 16) & 1u)) >> 16;
  return (unsigned short)r;
}

#define GLOAD_LDS16(g, l)                                                              \
  __builtin_amdgcn_global_load_lds((const __attribute__((address_space(1))) void*)(g), \
                                   (__attribute__((address_space(3))) void*)(l), 16, 0, 0)

// ---------------------------------------------------------------------------
// Fused elementwise prep: emb f32->bf16 (blocks <8000) and w1/w2 transpose+cvt.
// ---------------------------------------------------------------------------
__global__ __launch_bounds__(256) void cvtwt_kernel(
    const float* __restrict__ emb, unsigned short* __restrict__ embb,
    const float* __restrict__ w1, const float* __restrict__ w2,
    unsigned short* __restrict__ w1t, unsigned short* __restrict__ w2t) {
  const int blk = blockIdx.x;
  if (blk < 8000) {
    const long base = ((long)blk * 256 + threadIdx.x) * 8;
    float4 a = *(const float4*)&emb[base];
    float4 b = *(const float4*)&emb[base + 4];
    ushort8v o;
    o[0] = f2b(a.x); o[1] = f2b(a.y); o[2] = f2b(a.z); o[3] = f2b(a.w);
    o[4] = f2b(b.x); o[5] = f2b(b.y); o[6] = f2b(b.z); o[7] = f2b(b.w);
    *(ushort8v*)&embb[base] = o;
  } else {
    const int i = (blk - 8000) * 256 + threadIdx.x;
    if (i < ND * NH) {
      const int n = i >> 9, k = i & 511;
      w1t[i] = f2b(w1[k * NH + n]);
    } else {
      const int j = i - ND * NH;
      const int n = j >> 10, k = j & 1023;
      w2t[j] = f2b(w2[k * ND + n]);
    }
  }
}

// ---------------------------------------------------------------------------
// Tiled bf16 MFMA GEMM: Out = act(A @ Bt^T + bias) -> bf16.
// Tile 128x128, BK=32, 3-deep buffer pipeline with counted vmcnt, XOR-swizzled
// LDS, XCD-aware block swizzle, setprio around MFMA cluster. 4 waves (2x2).
// ---------------------------------------------------------------------------
template <int KDIM, int NLD, int NBN, bool GATHER, bool RELU>
__global__ __launch_bounds__(256) void gemm_kernel(
    const int* __restrict__ seq, const unsigned short* __restrict__ Abase,
    const unsigned short* __restrict__ Bt, const float* __restrict__ bias,
    unsigned short* __restrict__ Out) {
  __shared__ union {
    unsigned short AB[3][2][128 * 32];  // [buf][A/B][row*32 + chunk*8]
    unsigned short C[128 * 136];        // padded epilogue tile
  } sm;
  const int tid = threadIdx.x;
  const int lane = tid & 63;
  const int w = tid >> 6;

  const int id = blockIdx.x;
  const int swz = (id & 7) * (gridDim.x >> 3) + (id >> 3);
  const int bm = swz / NBN;
  const int bn = swz % NBN;

  const int wm = w >> 1, wn = w & 1;

  const int rgrp = lane >> 2;
  const int schunk = (lane & 3) ^ ((lane >> 3) & 3);
  const unsigned short* aptr[2];
  const unsigned short* bptr[2];
#pragma unroll
  for (int r = 0; r < 2; ++r) {
    const int grp = w * 2 + r;
    const int arow = bm * 128 + grp * 16 + rgrp;
    if constexpr (GATHER)
      aptr[r] = Abase + (size_t)seq[arow] * (size_t)KDIM + schunk * 8;
    else
      aptr[r] = Abase + (size_t)arow * (size_t)KDIM + schunk * 8;
    const int brow = bn * 128 + grp * 16 + rgrp;
    bptr[r] = Bt + (size_t)brow * (size_t)KDIM + schunk * 8;
  }

  const int fr = lane & 15;
  const int fhi = lane >> 4;
  const int fsw = (fr >> 1) & 3;
  const int fchunk = (fhi ^ fsw) * 8;
  int aoff[4], boff[4];
#pragma unroll
  for (int m = 0; m < 4; ++m) aoff[m] = (wm * 64 + m * 16 + fr) * 32 + fchunk;
#pragma unroll
  for (int n = 0; n < 4; ++n) boff[n] = (wn * 64 + n * 16 + fr) * 32 + fchunk;

  f32x4 acc[4][4] = {};

  auto stage = [&](int buf, int kt) {
#pragma unroll
    for (int r = 0; r < 2; ++r) {
      const int grp = w * 2 + r;
      GLOAD_LDS16(aptr[r] + kt * 32, &sm.AB[buf][0][grp * 512]);
      GLOAD_LDS16(bptr[r] + kt * 32, &sm.AB[buf][1][grp * 512]);
    }
  };

  constexpr int NKT = KDIM / 32;
  stage(0, 0);
  stage(1, 1);
  for (int kt = 0; kt < NKT; ++kt) {
    if (kt + 1 < NKT)
      asm volatile("s_waitcnt vmcnt(4)" ::: "memory");
    else
      asm volatile("s_waitcnt vmcnt(0)" ::: "memory");
    __builtin_amdgcn_s_barrier();
    if (kt + 2 < NKT) stage((kt + 2) % 3, kt + 2);
    const int cur = kt % 3;
    bf16x8 af[4], bfr[4];
#pragma unroll
    for (int m = 0; m < 4; ++m)
      af[m] = __builtin_bit_cast(bf16x8, *(const ushort8v*)&sm.AB[cur][0][aoff[m]]);
#pragma unroll
    for (int n = 0; n < 4; ++n)
      bfr[n] = __builtin_bit_cast(bf16x8, *(const ushort8v*)&sm.AB[cur][1][boff[n]]);
    __builtin_amdgcn_s_setprio(1);
#pragma unroll
    for (int m = 0; m < 4; ++m)
#pragma unroll
      for (int n = 0; n < 4; ++n)
        acc[m][n] = __builtin_amdgcn_mfma_f32_16x16x32_bf16(af[m], bfr[n], acc[m][n], 0, 0, 0);
    __builtin_amdgcn_s_setprio(0);
  }
  __builtin_amdgcn_s_barrier();

#pragma unroll
  for (int m = 0; m < 4; ++m)
#pragma unroll
    for (int n = 0; n < 4; ++n) {
      const int col_l = wn * 64 + n * 16 + fr;
      const float bb = bias[bn * 128 + col_l];
      const int row_l0 = wm * 64 + m * 16 + (fhi << 2);
#pragma unroll
      for (int i = 0; i < 4; ++i) {
        float v = acc[m][n][i] + bb;
        if constexpr (RELU) v = fmaxf(v, 0.f);
        sm.C[(row_l0 + i) * 136 + col_l] = f2b(v);
      }
    }
  __syncthreads();
#pragma unroll
  for (int r8 = 0; r8 < 8; ++r8) {
    const int chunk = r8 * 256 + tid;
    const int row = chunk >> 4;
    const int c8 = (chunk & 15) * 8;
    ushort8v v = *(const ushort8v*)&sm.C[row * 136 + c8];
    *(ushort8v*)&Out[(size_t)(bm * 128 + row) * (size_t)NLD + bn * 128 + c8] = v;
  }
}

// ---------------------------------------------------------------------------
// Fused residual + LayerNorm + gate (f32 math).
// ---------------------------------------------------------------------------
__global__ __launch_bounds__(256) void ln_gate_kernel(
    const int* __restrict__ seq, const float* __restrict__ emb,
    const unsigned short* __restrict__ FF, unsigned short* __restrict__ H,
    const float* __restrict__ ln_g, const float* __restrict__ ln_b,
    const float* __restrict__ wg, const float* __restrict__ bgp,
    float* __restrict__ gate, float* __restrict__ hlast) {
  const int lane = threadIdx.x & 63;
  const int w = threadIdx.x >> 6;
  const int t = blockIdx.x * 4 + w;
  const float* er = emb + (size_t)seq[t] * ND + lane * 8;
  ushort8v fv = *(const ushort8v*)&FF[(size_t)t * ND + lane * 8];
  float4 e0 = *(const float4*)er, e1 = *(const float4*)(er + 4);
  float x[8] = {b2f(fv[0]) + e0.x, b2f(fv[1]) + e0.y, b2f(fv[2]) + e0.z, b2f(fv[3]) + e0.w,
                b2f(fv[4]) + e1.x, b2f(fv[5]) + e1.y, b2f(fv[6]) + e1.z, b2f(fv[7]) + e1.w};
  float s = 0.f, sq = 0.f;
#pragma unroll
  for (int j = 0; j < 8; ++j) {
    s += x[j];
    sq += x[j] * x[j];
  }
#pragma unroll
  for (int o = 32; o; o >>= 1) {
    s += __shfl_xor(s, o);
    sq += __shfl_xor(sq, o);
  }
  const float mu = s * (1.f / 512.f);
  const float var = sq * (1.f / 512.f) - mu * mu;
  const float rs = rsqrtf(var + 1e-5f);
  float gd = 0.f;
  float h[8];
  ushort8v hv;
#pragma unroll
  for (int j = 0; j < 8; ++j) {
    const int col = lane * 8 + j;
    h[j] = (x[j] - mu) * rs * ln_g[col] + ln_b[col];
    hv[j] = f2b(h[j]);
    gd += h[j] * wg[col];
  }
  *(ushort8v*)&H[(size_t)t * ND + lane * 8] = hv;
#pragma unroll
  for (int o = 32; o; o >>= 1) gd += __shfl_xor(gd, o);
  if (lane == 0) gate[t] = 1.f / (1.f + expf(-(gd + bgp[0])));
  if ((t & (NT - 1)) == NT - 1) {
    const int b = t >> 12;
    float* hl = hlast + b * ND + lane * 8;
#pragma unroll
    for (int j = 0; j < 8; ++j) hl[j] = h[j];
  }
}

// ---------------------------------------------------------------------------
// Top-256 of 4096 per batch: radix threshold search on positive f32 bits.
// ---------------------------------------------------------------------------
__global__ __launch_bounds__(256) void topk_kernel(const float* __restrict__ gate,
                                                   int* __restrict__ topidx) {
  __shared__ unsigned int keys[NT];
  __shared__ int cnt;
  __shared__ int scan[256];
  const int b = blockIdx.x, tid = threadIdx.x;
  const float* g = gate + (size_t)b * NT;
  for (int i = tid; i < NT; i += 256) keys[i] = __builtin_bit_cast(unsigned int, g[i]);
  __syncthreads();
  unsigned int K = 0u;
  for (int bit = 31; bit >= 0; --bit) {
    const unsigned int cand = K | (1u << bit);
    if (tid == 0) cnt = 0;
    __syncthreads();
    int c = 0;
    for (int i = tid * 16; i < tid * 16 + 16; ++i) c += (keys[i] >= cand) ? 1 : 0;
    if (c) atomicAdd(&cnt, c);
    __syncthreads();
    const int cn = cnt;
    __syncthreads();
    if (cn >= NSLOTS) K = cand;
  }
  int gcnt = 0, ecnt = 0;
  for (int i = tid * 16; i < tid * 16 + 16; ++i) {
    gcnt += (keys[i] > K) ? 1 : 0;
    ecnt += (keys[i] == K) ? 1 : 0;
  }
  scan[tid] = gcnt;
  __syncthreads();
  for (int off = 1; off < 256; off <<= 1) {
    int v2 = (tid >= off) ? scan[tid - off] : 0;
    __syncthreads();
    scan[tid] += v2;
    __syncthreads();
  }
  const int gi = scan[tid];
  const int tot_gt = scan[255];
  __syncthreads();
  scan[tid] = ecnt;
  __syncthreads();
  for (int off = 1; off < 256; off <<= 1) {
    int v2 = (tid >= off) ? scan[tid - off] : 0;
    __syncthreads();
    scan[tid] += v2;
    __syncthreads();
  }
  const int ei = scan[tid];
  int gpos = gi - gcnt;
  int epos = tot_gt + (ei - ecnt);
  int* outp = topidx + b * NSLOTS;
  for (int i = tid * 16; i < tid * 16 + 16; ++i) {
    if (keys[i] > K) {
      outp[gpos++] = i;
    } else if (keys[i] == K) {
      if (epos < NSLOTS) outp[epos] = i;
      epos++;
    }
  }
}

// ---------------------------------------------------------------------------
// qpart[b][s][c] = sum_{d in slice s} hlast[b][d]*wq[d][c]  (+bq when s==0)
// 128 blocks = 16 b x 8 slices of 64 d. hlast read scalar (uniform).
// ---------------------------------------------------------------------------
__global__ __launch_bounds__(256) void qpart_kernel(const float* __restrict__ hlast,
                                                    const float* __restrict__ wq,
                                                    const float* __restrict__ bq,
                                                    float* __restrict__ qpart) {
  const int blk = blockIdx.x;
  const int b = blk >> 3, s = blk & 7;
  const int c0 = threadIdx.x;
  const int d0 = s * 64;
  float a0 = 0.f, a1 = 0.f;
#pragma unroll 4
  for (int dd = 0; dd < 64; ++dd) {
    const float hv = hlast[b * ND + d0 + dd];
    a0 += hv * wq[(size_t)(d0 + dd) * ND + c0];
    a1 += hv * wq[(size_t)(d0 + dd) * ND + c0 + 256];
  }
  if (s == 0) {
    a0 += bq[c0];
    a1 += bq[c0 + 256];
  }
  float* qp = qpart + ((size_t)b * 8 + s) * ND;
  qp[c0] = a0;
  qp[c0 + 256] = a1;
}

// ---------------------------------------------------------------------------
// Fused scores + softmax + ctx (one block per batch; H is bf16).
// qs = sum of 8 qpart slices.
// ---------------------------------------------------------------------------
__global__ __launch_bounds__(256) void attn_kernel(
    const unsigned short* __restrict__ H, const float* __restrict__ qpart,
    const int* __restrict__ topidx, float* __restrict__ ctx) {
  __shared__ float qs[512];
  __shared__ float attn[256];
  __shared__ int idxs[256];
  __shared__ float red[4];
  const int b = blockIdx.x, tid = threadIdx.x;
  const int lane = tid & 63, wv = tid >> 6;
  {
    float a0 = 0.f, a1 = 0.f;
#pragma unroll
    for (int s = 0; s < 8; ++s) {
      const float* qp = qpart + ((size_t)b * 8 + s) * ND;
      a0 += qp[tid];
      a1 += qp[tid + 256];
    }
    qs[tid] = a0;
    qs[tid + 256] = a1;
  }
  idxs[tid] = topidx[b * 256 + tid];
  __syncthreads();
  const unsigned short* hr = H + ((size_t)b * NT + idxs[tid]) * ND;
  float sc = 0.f;
  for (int d0 = 0; d0 < 512; d0 += 8) {
    ushort8v hv = *(const ushort8v*)&hr[d0];
#pragma unroll
    for (int j = 0; j < 8; ++j) sc += b2f(hv[j]) * qs[d0 + j];
  }
  float m = sc;
#pragma unroll
  for (int o = 32; o; o >>= 1) m = fmaxf(m, __shfl_xor(m, o));
  if (lane == 0) red[wv] = m;
  __syncthreads();
  m = fmaxf(fmaxf(red[0], red[1]), fmaxf(red[2], red[3]));
  __syncthreads();
  const float e = expf(sc - m);
  float ssum = e;
#pragma unroll
  for (int o = 32; o; o >>= 1) ssum += __shfl_xor(ssum, o);
  if (lane == 0) red[wv] = ssum;
  __syncthreads();
  ssum = red[0] + red[1] + red[2] + red[3];
  attn[tid] = e / ssum;
  __syncthreads();
  for (int d = tid; d < 512; d += 256) {
    float c = 0.f;
    for (int k = 0; k < 256; ++k) c += attn[k] * b2f(H[((size_t)b * NT + idxs[k]) * ND + d]);
    ctx[b * 512 + d] = c;
  }
}

// ---------------------------------------------------------------------------
// Out-projection stage 1: part[s][b][v] = sum_{d in slice s(32)} ctx[b][d]*wo[d][v]
// 2000 blocks = 125 col-tiles x 16 slices. ctx read scalar (uniform address).
// ---------------------------------------------------------------------------
__global__ __launch_bounds__(256) void out_part_kernel(const float* __restrict__ ctx,
                                                       const float* __restrict__ wo,
                                                       float* __restrict__ part) {
  const int blk = blockIdx.x;
  const int ct = blk % 125, s = blk / 125;
  const int v = ct * 256 + threadIdx.x;
  const int d0 = s * 32;
  const float* wp = wo + (size_t)d0 * NV + v;
  float acc[16] = {};
#pragma unroll 4
  for (int dd = 0; dd < 32; ++dd) {
    const float wv = wp[(size_t)dd * NV];
#pragma unroll
    for (int bb = 0; bb < 16; ++bb) acc[bb] += ctx[bb * ND + d0 + dd] * wv;
  }
  float* pp = part + (size_t)s * NB * NV + v;
#pragma unroll
  for (int bb = 0; bb < 16; ++bb) pp[(size_t)bb * NV] = acc[bb];
}

// ---------------------------------------------------------------------------
// Out-projection stage 2: out[b][v] = sum_s part[s][b][v] + bo[v]
// ---------------------------------------------------------------------------
__global__ __launch_bounds__(256) void out_reduce_kernel(const float* __restrict__ part,
                                                         const float* __restrict__ bo,
                                                         float* __restrict__ out) {
  const int i = blockIdx.x * 256 + threadIdx.x;  // over 16*32000
  const int b = i / NV;
  const int v = i - b * NV;
  float a = bo[v];
#pragma unroll
  for (int s = 0; s < 16; ++s) a += part[(size_t)s * NB * NV + i];
  out[i] = a;
}

// ---------------------------------------------------------------------------
// Workspace layout (total 194.0 MiB):
//   A1     @ 0        : 128 MiB (gemm1 out). After gemm2: bytes 0..64Mi = H,
//                       bytes 64Mi..96.8Mi = out-projection partials (32.8 MB).
//   region @ 128 MiB  : 64 MiB — embb (phase 1), then FF bf16 (phase 2)
//   w1t    @ 192 MiB  : 1 MiB — dead after gemm1; aliased by small buffers
//   w2t    @ 193 MiB  : 1 MiB — dead after gemm2
// ---------------------------------------------------------------------------
extern "C" void kernel_launch(void* const* d_in, const int* in_sizes, int n_in,
                              void* d_out, int out_size, void* d_ws, size_t ws_size,
                              hipStream_t stream) {
  const int* seq = (const int*)d_in[0];
  const float* emb = (const float*)d_in[1];
  const float* w1 = (const float*)d_in[2];
  const float* b1 = (const float*)d_in[3];
  const float* w2 = (const float*)d_in[4];
  const float* b2 = (const float*)d_in[5];
  const float* ln_g = (const float*)d_in[6];
  const float* ln_b = (const float*)d_in[7];
  const float* wg = (const float*)d_in[8];
  const float* bg = (const float*)d_in[9];
  const float* wq = (const float*)d_in[10];
  const float* bq = (const float*)d_in[11];
  const float* wo = (const float*)d_in[12];
  const float* bo = (const float*)d_in[13];
  float* out = (float*)d_out;

  char* ws = (char*)d_ws;
  unsigned short* A1 = (unsigned short*)ws;                       // 128 MiB
  float* part = (float*)(ws + ((size_t)64 << 20));                // 32.8 MB (A1 upper half, dead after gemm2)
  unsigned short* region = (unsigned short*)(ws + ((size_t)128 << 20));
  unsigned short* embb = region;                                  // phase 1
  unsigned short* FF = region;                                    // phase 2
  unsigned short* w1t = (unsigned short*)(ws + ((size_t)192 << 20));
  unsigned short* w2t = (unsigned short*)(ws + ((size_t)193 << 20));
  char* sb = ws + ((size_t)192 << 20);
  float* gate = (float*)sb;                                       // 256 KiB
  int* topidx = (int*)(sb + 262144);                              // 16 KiB
  float* hlast = (float*)(sb + 262144 + 16384);                   // 32 KiB
  float* ctxbuf = (float*)(sb + 262144 + 16384 + 32768);          // 32 KiB
  float* qpart = (float*)(sb + 262144 + 16384 + 65536);           // 256 KiB
  unsigned short* H = A1;                                         // A1 dead after gemm2

  cvtwt_kernel<<<12096, 256, 0, stream>>>(emb, embb, w1, w2, w1t, w2t);
  gemm_kernel<512, 1024, 8, true, true>
      <<<4096, 256, 0, stream>>>(seq, embb, w1t, b1, A1);
  gemm_kernel<1024, 512, 4, false, false>
      <<<2048, 256, 0, stream>>>(nullptr, A1, w2t, b2, FF);
  ln_gate_kernel<<<16384, 256, 0, stream>>>(seq, emb, FF, H, ln_g, ln_b, wg, bg, gate, hlast);
  topk_kernel<<<16, 256, 0, stream>>>(gate, topidx);
  qpart_kernel<<<128, 256, 0, stream>>>(hlast, wq, bq, qpart);
  attn_kernel<<<16, 256, 0, stream>>>(H, qpart, topidx, ctxbuf);
  out_part_kernel<<<2000, 256, 0, stream>>>(ctxbuf, wo, part);
  out_reduce_kernel<<<2000, 256, 0, stream>>>(part, bo, out);
}

// Round 7
// 333.575 us; speedup vs baseline: 1.3743x; 1.0724x over previous
//
#include <hip/hip_runtime.h>

typedef __bf16 bf16x8 __attribute__((ext_vector_type(8)));
typedef float f32x4 __attribute__((ext_vector_type(4)));
typedef unsigned short ushort8v __attribute__((ext_vector_type(8)));

#define NB 16
#define NT 4096
#define NV 32000
#define ND 512
#define NH 1024
#define NSLOTS 256

__device__ __forceinline__ float b2f(unsigned short u) {
  unsigned int x = ((unsigned int)u) << 16;
  return __builtin_bit_cast(float, x);
}
__device__ __forceinline__ unsigned short f2b(float f) {
  unsigned int x = __builtin_bit_cast(unsigned int, f);
  unsigned int r = (x + 0x7FFFu + ((x >> 16) & 1u)) >> 16;
  return (unsigned short)r;
}

#define GLOAD_LDS16(g, l)                                                              \
  __builtin_amdgcn_global_load_lds((const __attribute__((address_space(1))) void*)(g), \
                                   (__attribute__((address_space(3))) void*)(l), 16, 0, 0)

// ---------------------------------------------------------------------------
// Fused elementwise prep: emb f32->bf16 (blocks <8000) and w1/w2 transpose+cvt.
// ---------------------------------------------------------------------------
__global__ __launch_bounds__(256) void cvtwt_kernel(
    const float* __restrict__ emb, unsigned short* __restrict__ embb,
    const float* __restrict__ w1, const float* __restrict__ w2,
    unsigned short* __restrict__ w1t, unsigned short* __restrict__ w2t) {
  const int blk = blockIdx.x;
  if (blk < 8000) {
    const long base = ((long)blk * 256 + threadIdx.x) * 8;
    float4 a = *(const float4*)&emb[base];
    float4 b = *(const float4*)&emb[base + 4];
    ushort8v o;
    o[0] = f2b(a.x); o[1] = f2b(a.y); o[2] = f2b(a.z); o[3] = f2b(a.w);
    o[4] = f2b(b.x); o[5] = f2b(b.y); o[6] = f2b(b.z); o[7] = f2b(b.w);
    *(ushort8v*)&embb[base] = o;
  } else {
    const int i = (blk - 8000) * 256 + threadIdx.x;
    if (i < ND * NH) {
      const int n = i >> 9, k = i & 511;
      w1t[i] = f2b(w1[k * NH + n]);
    } else {
      const int j = i - ND * NH;
      const int n = j >> 10, k = j & 1023;
      w2t[j] = f2b(w2[k * ND + n]);
    }
  }
}

// ---------------------------------------------------------------------------
// 256x256 bf16 MFMA GEMM: Out = act(A @ Bt^T + bias) -> bf16.
// 8 waves (2M x 4N), per-wave 128x64 output, BK=64, 2-deep LDS double buffer
// (dynamic 128 KiB), (row&7) XOR chunk swizzle (both-sides), XCD block
// swizzle, setprio MFMA clusters. Stage issued before ds_read+MFMA so the
// end-of-tile drain is hidden under ~2000cy of compute.
// ---------------------------------------------------------------------------
template <int KDIM, int NLD, int NBN, bool GATHER, bool RELU>
__global__ __launch_bounds__(512, 2) void gemm256_kernel(
    const int* __restrict__ seq, const unsigned short* __restrict__ Abase,
    const unsigned short* __restrict__ Bt, const float* __restrict__ bias,
    unsigned short* __restrict__ Out) {
  extern __shared__ unsigned short smraw[];  // [buf][A 16384 | B 16384] shorts
  const int tid = threadIdx.x;
  const int lane = tid & 63;
  const int w = tid >> 6;   // 0..7
  const int wm = w >> 2;    // 0..1
  const int wn = w & 3;     // 0..3

  const int id = blockIdx.x;
  const int swz = (id & 7) * (gridDim.x >> 3) + (id >> 3);
  const int bm = swz / NBN;
  const int bn = swz % NBN;

  // Staging source pointers. Stage instruction (r, wave w) covers LDS 16B
  // chunks c_lin = r*512 + w*64 + lane: row = c_lin>>3, dstchunk = c_lin&7.
  // LDS slot (row, c) must hold global chunk c ^ (row&7)  -> src chunk.
  const unsigned short* aSrc[4];
  const unsigned short* bSrc[4];
#pragma unroll
  for (int r = 0; r < 4; ++r) {
    const int row = r * 64 + w * 8 + (lane >> 3);
    const int sc = (lane & 7) ^ (row & 7);
    long arowg;
    if constexpr (GATHER)
      arowg = seq[bm * 256 + row];
    else
      arowg = bm * 256 + row;
    aSrc[r] = Abase + (size_t)arowg * KDIM + sc * 8;
    bSrc[r] = Bt + (size_t)(bn * 256 + row) * KDIM + sc * 8;
  }

  const int fr = lane & 15;
  const int hi = lane >> 4;

  f32x4 acc[8][4] = {};

  auto stage = [&](int buf, int kt) {
    unsigned short* A = smraw + buf * 32768;
    unsigned short* B = A + 16384;
#pragma unroll
    for (int r = 0; r < 4; ++r) {
      GLOAD_LDS16(aSrc[r] + kt * 64, &A[(r * 512 + w * 64) * 8]);
      GLOAD_LDS16(bSrc[r] + kt * 64, &B[(r * 512 + w * 64) * 8]);
    }
  };

  constexpr int NKT = KDIM / 64;
  stage(0, 0);
  __syncthreads();  // drain prologue stage
  int cur = 0;
  for (int kt = 0; kt < NKT; ++kt) {
    if (kt + 1 < NKT) stage(cur ^ 1, kt + 1);  // issue early, drains at loop-end sync
    const unsigned short* A = smraw + cur * 32768;
    const unsigned short* B = A + 16384;
#pragma unroll
    for (int kk = 0; kk < 2; ++kk) {
      bf16x8 af[8], bf[4];
      const int ccd = (((kk * 4 + hi) ^ (fr & 7)) * 8);
#pragma unroll
      for (int m = 0; m < 8; ++m)
        af[m] = __builtin_bit_cast(bf16x8,
                 *(const ushort8v*)&A[(wm * 128 + m * 16 + fr) * 64 + ccd]);
#pragma unroll
      for (int n = 0; n < 4; ++n)
        bf[n] = __builtin_bit_cast(bf16x8,
                 *(const ushort8v*)&B[(wn * 64 + n * 16 + fr) * 64 + ccd]);
      __builtin_amdgcn_s_setprio(1);
#pragma unroll
      for (int m = 0; m < 8; ++m)
#pragma unroll
        for (int n = 0; n < 4; ++n)
          acc[m][n] = __builtin_amdgcn_mfma_f32_16x16x32_bf16(af[m], bf[n], acc[m][n], 0, 0, 0);
      __builtin_amdgcn_s_setprio(0);
    }
    __syncthreads();  // drains stage kt+1; WAR-protects buf[cur^1]
    cur ^= 1;
  }

  // Epilogue: bias (+relu); repack through LDS [128][264] in two row-halves.
  float bb[4];
#pragma unroll
  for (int n = 0; n < 4; ++n) bb[n] = bias[bn * 256 + wn * 64 + n * 16 + fr];
  unsigned short* C = smraw;
#pragma unroll
  for (int h = 0; h < 2; ++h) {
    if (h) __syncthreads();  // half-0 copy finished before half-1 writes
    if (wm == h) {
#pragma unroll
      for (int m = 0; m < 8; ++m)
#pragma unroll
        for (int n = 0; n < 4; ++n)
#pragma unroll
          for (int i = 0; i < 4; ++i) {
            float v = acc[m][n][i] + bb[n];
            if constexpr (RELU) v = fmaxf(v, 0.f);
            C[(m * 16 + hi * 4 + i) * 264 + wn * 64 + n * 16 + fr] = f2b(v);
          }
    }
    __syncthreads();
#pragma unroll
    for (int it = 0; it < 8; ++it) {
      const int idx = it * 512 + tid;
      const int lrow = idx >> 5;
      const int pos = idx & 31;
      ushort8v v = *(const ushort8v*)&C[lrow * 264 + pos * 8];
      *(ushort8v*)&Out[(size_t)(bm * 256 + h * 128 + lrow) * (size_t)NLD + bn * 256 + pos * 8] = v;
    }
  }
}

// ---------------------------------------------------------------------------
// Fused residual + LayerNorm + gate (f32 math).
// ---------------------------------------------------------------------------
__global__ __launch_bounds__(256) void ln_gate_kernel(
    const int* __restrict__ seq, const float* __restrict__ emb,
    const unsigned short* __restrict__ FF, unsigned short* __restrict__ H,
    const float* __restrict__ ln_g, const float* __restrict__ ln_b,
    const float* __restrict__ wg, const float* __restrict__ bgp,
    float* __restrict__ gate, float* __restrict__ hlast) {
  const int lane = threadIdx.x & 63;
  const int w = threadIdx.x >> 6;
  const int t = blockIdx.x * 4 + w;
  const float* er = emb + (size_t)seq[t] * ND + lane * 8;
  ushort8v fv = *(const ushort8v*)&FF[(size_t)t * ND + lane * 8];
  float4 e0 = *(const float4*)er, e1 = *(const float4*)(er + 4);
  float x[8] = {b2f(fv[0]) + e0.x, b2f(fv[1]) + e0.y, b2f(fv[2]) + e0.z, b2f(fv[3]) + e0.w,
                b2f(fv[4]) + e1.x, b2f(fv[5]) + e1.y, b2f(fv[6]) + e1.z, b2f(fv[7]) + e1.w};
  float s = 0.f, sq = 0.f;
#pragma unroll
  for (int j = 0; j < 8; ++j) {
    s += x[j];
    sq += x[j] * x[j];
  }
#pragma unroll
  for (int o = 32; o; o >>= 1) {
    s += __shfl_xor(s, o);
    sq += __shfl_xor(sq, o);
  }
  const float mu = s * (1.f / 512.f);
  const float var = sq * (1.f / 512.f) - mu * mu;
  const float rs = rsqrtf(var + 1e-5f);
  float gd = 0.f;
  float h[8];
  ushort8v hv;
#pragma unroll
  for (int j = 0; j < 8; ++j) {
    const int col = lane * 8 + j;
    h[j] = (x[j] - mu) * rs * ln_g[col] + ln_b[col];
    hv[j] = f2b(h[j]);
    gd += h[j] * wg[col];
  }
  *(ushort8v*)&H[(size_t)t * ND + lane * 8] = hv;
#pragma unroll
  for (int o = 32; o; o >>= 1) gd += __shfl_xor(gd, o);
  if (lane == 0) gate[t] = 1.f / (1.f + expf(-(gd + bgp[0])));
  if ((t & (NT - 1)) == NT - 1) {
    const int b = t >> 12;
    float* hl = hlast + b * ND + lane * 8;
#pragma unroll
    for (int j = 0; j < 8; ++j) hl[j] = h[j];
  }
}

// ---------------------------------------------------------------------------
// Top-256 of 4096 per batch: radix threshold search on positive f32 bits.
// ---------------------------------------------------------------------------
__global__ __launch_bounds__(256) void topk_kernel(const float* __restrict__ gate,
                                                   int* __restrict__ topidx) {
  __shared__ unsigned int keys[NT];
  __shared__ int cnt;
  __shared__ int scan[256];
  const int b = blockIdx.x, tid = threadIdx.x;
  const float* g = gate + (size_t)b * NT;
  for (int i = tid; i < NT; i += 256) keys[i] = __builtin_bit_cast(unsigned int, g[i]);
  __syncthreads();
  unsigned int K = 0u;
  for (int bit = 31; bit >= 0; --bit) {
    const unsigned int cand = K | (1u << bit);
    if (tid == 0) cnt = 0;
    __syncthreads();
    int c = 0;
    for (int i = tid * 16; i < tid * 16 + 16; ++i) c += (keys[i] >= cand) ? 1 : 0;
    if (c) atomicAdd(&cnt, c);
    __syncthreads();
    const int cn = cnt;
    __syncthreads();
    if (cn >= NSLOTS) K = cand;
  }
  int gcnt = 0, ecnt = 0;
  for (int i = tid * 16; i < tid * 16 + 16; ++i) {
    gcnt += (keys[i] > K) ? 1 : 0;
    ecnt += (keys[i] == K) ? 1 : 0;
  }
  scan[tid] = gcnt;
  __syncthreads();
  for (int off = 1; off < 256; off <<= 1) {
    int v2 = (tid >= off) ? scan[tid - off] : 0;
    __syncthreads();
    scan[tid] += v2;
    __syncthreads();
  }
  const int gi = scan[tid];
  const int tot_gt = scan[255];
  __syncthreads();
  scan[tid] = ecnt;
  __syncthreads();
  for (int off = 1; off < 256; off <<= 1) {
    int v2 = (tid >= off) ? scan[tid - off] : 0;
    __syncthreads();
    scan[tid] += v2;
    __syncthreads();
  }
  const int ei = scan[tid];
  int gpos = gi - gcnt;
  int epos = tot_gt + (ei - ecnt);
  int* outp = topidx + b * NSLOTS;
  for (int i = tid * 16; i < tid * 16 + 16; ++i) {
    if (keys[i] > K) {
      outp[gpos++] = i;
    } else if (keys[i] == K) {
      if (epos < NSLOTS) outp[epos] = i;
      epos++;
    }
  }
}

// ---------------------------------------------------------------------------
// qpart[b][s][c] = sum_{d in slice s} hlast[b][d]*wq[d][c]  (+bq when s==0)
// ---------------------------------------------------------------------------
__global__ __launch_bounds__(256) void qpart_kernel(const float* __restrict__ hlast,
                                                    const float* __restrict__ wq,
                                                    const float* __restrict__ bq,
                                                    float* __restrict__ qpart) {
  const int blk = blockIdx.x;
  const int b = blk >> 3, s = blk & 7;
  const int c0 = threadIdx.x;
  const int d0 = s * 64;
  float a0 = 0.f, a1 = 0.f;
#pragma unroll 4
  for (int dd = 0; dd < 64; ++dd) {
    const float hv = hlast[b * ND + d0 + dd];
    a0 += hv * wq[(size_t)(d0 + dd) * ND + c0];
    a1 += hv * wq[(size_t)(d0 + dd) * ND + c0 + 256];
  }
  if (s == 0) {
    a0 += bq[c0];
    a1 += bq[c0 + 256];
  }
  float* qp = qpart + ((size_t)b * 8 + s) * ND;
  qp[c0] = a0;
  qp[c0 + 256] = a1;
}

// ---------------------------------------------------------------------------
// Fused scores + softmax + ctx. 64 blocks = 16 batches x 4 d-chunks of 128.
// Scores/softmax computed redundantly per chunk (cheap, deterministic).
// ---------------------------------------------------------------------------
__global__ __launch_bounds__(256) void attn_kernel(
    const unsigned short* __restrict__ H, const float* __restrict__ qpart,
    const int* __restrict__ topidx, float* __restrict__ ctx) {
  __shared__ float qs[512];
  __shared__ float attnv[256];
  __shared__ int idxs[256];
  __shared__ float red[4];
  __shared__ float part[2][128];
  const int blk = blockIdx.x;
  const int b = blk >> 2, dc = blk & 3;
  const int tid = threadIdx.x;
  const int lane = tid & 63, wv = tid >> 6;
  {
    float a0 = 0.f, a1 = 0.f;
#pragma unroll
    for (int s = 0; s < 8; ++s) {
      const float* qp = qpart + ((size_t)b * 8 + s) * ND;
      a0 += qp[tid];
      a1 += qp[tid + 256];
    }
    qs[tid] = a0;
    qs[tid + 256] = a1;
  }
  idxs[tid] = topidx[b * 256 + tid];
  __syncthreads();
  const unsigned short* hr = H + ((size_t)b * NT + idxs[tid]) * ND;
  float sc = 0.f;
  for (int d0 = 0; d0 < 512; d0 += 8) {
    ushort8v hv = *(const ushort8v*)&hr[d0];
#pragma unroll
    for (int j = 0; j < 8; ++j) sc += b2f(hv[j]) * qs[d0 + j];
  }
  float m = sc;
#pragma unroll
  for (int o = 32; o; o >>= 1) m = fmaxf(m, __shfl_xor(m, o));
  if (lane == 0) red[wv] = m;
  __syncthreads();
  m = fmaxf(fmaxf(red[0], red[1]), fmaxf(red[2], red[3]));
  __syncthreads();
  const float e = expf(sc - m);
  float ssum = e;
#pragma unroll
  for (int o = 32; o; o >>= 1) ssum += __shfl_xor(ssum, o);
  if (lane == 0) red[wv] = ssum;
  __syncthreads();
  ssum = red[0] + red[1] + red[2] + red[3];
  attnv[tid] = e / ssum;
  __syncthreads();
  const int d = dc * 128 + (tid & 127);
  const int kh = tid >> 7;
  float c = 0.f;
#pragma unroll 4
  for (int k2 = 0; k2 < 128; ++k2) {
    const int k = kh * 128 + k2;
    c += attnv[k] * b2f(H[((size_t)b * NT + idxs[k]) * ND + d]);
  }
  part[kh][tid & 127] = c;
  __syncthreads();
  if (tid < 128) ctx[b * 512 + dc * 128 + tid] = part[0][tid] + part[1][tid];
}

// ---------------------------------------------------------------------------
// Out-projection stage 1: part[s][b][v] = sum_{d in slice s(32)} ctx[b][d]*wo[d][v]
// ---------------------------------------------------------------------------
__global__ __launch_bounds__(256) void out_part_kernel(const float* __restrict__ ctx,
                                                       const float* __restrict__ wo,
                                                       float* __restrict__ part) {
  const int blk = blockIdx.x;
  const int ct = blk % 125, s = blk / 125;
  const int v = ct * 256 + threadIdx.x;
  const int d0 = s * 32;
  const float* wp = wo + (size_t)d0 * NV + v;
  float acc[16] = {};
#pragma unroll 4
  for (int dd = 0; dd < 32; ++dd) {
    const float wv = wp[(size_t)dd * NV];
#pragma unroll
    for (int bb = 0; bb < 16; ++bb) acc[bb] += ctx[bb * ND + d0 + dd] * wv;
  }
  float* pp = part + (size_t)s * NB * NV + v;
#pragma unroll
  for (int bb = 0; bb < 16; ++bb) pp[(size_t)bb * NV] = acc[bb];
}

// ---------------------------------------------------------------------------
// Out-projection stage 2: out[b][v] = sum_s part[s][b][v] + bo[v]
// ---------------------------------------------------------------------------
__global__ __launch_bounds__(256) void out_reduce_kernel(const float* __restrict__ part,
                                                         const float* __restrict__ bo,
                                                         float* __restrict__ out) {
  const int i = blockIdx.x * 256 + threadIdx.x;
  const int b = i / NV;
  const int v = i - b * NV;
  float a = bo[v];
#pragma unroll
  for (int s = 0; s < 16; ++s) a += part[(size_t)s * NB * NV + i];
  out[i] = a;
}

// ---------------------------------------------------------------------------
// Workspace layout (total 194.0 MiB):
//   A1     @ 0        : 128 MiB (gemm1 out). After gemm2: 0..64Mi = H,
//                       64Mi..96.8Mi = out-projection partials.
//   region @ 128 MiB  : 64 MiB — embb (phase 1), then FF bf16 (phase 2)
//   w1t    @ 192 MiB  : 1 MiB — dead after gemm1; aliased by small buffers
//   w2t    @ 193 MiB  : 1 MiB
// ---------------------------------------------------------------------------
extern "C" void kernel_launch(void* const* d_in, const int* in_sizes, int n_in,
                              void* d_out, int out_size, void* d_ws, size_t ws_size,
                              hipStream_t stream) {
  const int* seq = (const int*)d_in[0];
  const float* emb = (const float*)d_in[1];
  const float* w1 = (const float*)d_in[2];
  const float* b1 = (const float*)d_in[3];
  const float* w2 = (const float*)d_in[4];
  const float* b2 = (const float*)d_in[5];
  const float* ln_g = (const float*)d_in[6];
  const float* ln_b = (const float*)d_in[7];
  const float* wg = (const float*)d_in[8];
  const float* bg = (const float*)d_in[9];
  const float* wq = (const float*)d_in[10];
  const float* bq = (const float*)d_in[11];
  const float* wo = (const float*)d_in[12];
  const float* bo = (const float*)d_in[13];
  float* out = (float*)d_out;

  char* ws = (char*)d_ws;
  unsigned short* A1 = (unsigned short*)ws;                       // 128 MiB
  float* part = (float*)(ws + ((size_t)64 << 20));                // A1 upper half (dead after gemm2)
  unsigned short* region = (unsigned short*)(ws + ((size_t)128 << 20));
  unsigned short* embb = region;                                  // phase 1
  unsigned short* FF = region;                                    // phase 2
  unsigned short* w1t = (unsigned short*)(ws + ((size_t)192 << 20));
  unsigned short* w2t = (unsigned short*)(ws + ((size_t)193 << 20));
  char* sb = ws + ((size_t)192 << 20);
  float* gate = (float*)sb;                                       // 256 KiB
  int* topidx = (int*)(sb + 262144);                              // 16 KiB
  float* hlast = (float*)(sb + 262144 + 16384);                   // 32 KiB
  float* ctxbuf = (float*)(sb + 262144 + 16384 + 32768);          // 32 KiB
  float* qpart = (float*)(sb + 262144 + 16384 + 65536);           // 256 KiB
  unsigned short* H = A1;                                         // A1 dead after gemm2

  // Allow 128 KiB dynamic LDS for the 256^2 GEMMs (idempotent, capture-safe).
  hipFuncSetAttribute(reinterpret_cast<const void*>(gemm256_kernel<512, 1024, 4, true, true>),
                      hipFuncAttributeMaxDynamicSharedMemorySize, 131072);
  hipFuncSetAttribute(reinterpret_cast<const void*>(gemm256_kernel<1024, 512, 2, false, false>),
                      hipFuncAttributeMaxDynamicSharedMemorySize, 131072);

  cvtwt_kernel<<<12096, 256, 0, stream>>>(emb, embb, w1, w2, w1t, w2t);
  gemm256_kernel<512, 1024, 4, true, true>
      <<<1024, 512, 131072, stream>>>(seq, embb, w1t, b1, A1);
  gemm256_kernel<1024, 512, 2, false, false>
      <<<512, 512, 131072, stream>>>(nullptr, A1, w2t, b2, FF);
  ln_gate_kernel<<<16384, 256, 0, stream>>>(seq, emb, FF, H, ln_g, ln_b, wg, bg, gate, hlast);
  topk_kernel<<<16, 256, 0, stream>>>(gate, topidx);
  qpart_kernel<<<128, 256, 0, stream>>>(hlast, wq, bq, qpart);
  attn_kernel<<<64, 256, 0, stream>>>(H, qpart, topidx, ctxbuf);
  out_part_kernel<<<2000, 256, 0, stream>>>(ctxbuf, wo, part);
  out_reduce_kernel<<<2000, 256, 0, stream>>>(part, bo, out);
}